// Round 1
// baseline (2472.945 us; speedup 1.0000x reference)
//
#include <hip/hip_runtime.h>
#include <stdint.h>
#include <stddef.h>

// NCA fused kernel for MI355X (gfx950).
// Reference: per step  h += MLP(conv3x3(h))  with conv weights spatially
// transposed by the torch transpose(-3,-1) trick:
//   p[b,y,x,o] = sum_{i,dy,dx} h[b,y+dy,x+dx,i] * conv_w[o,i,dx+1,dy+1]
// conv+fc_first fused:  ds1 = relu(patch @ W1c^T + b_first),
//   W1c[n][k=(tap,i)] = sum_o w_first[n][o]*conv_w[o,i,dx+1,dy+1]
//
// d_out layout: [x_final (2,097,152 f32)][history (17 x 2,097,152 f32)]
// history slot s is the h-state ping-pong buffer for step s.

typedef __bf16 bf16_t;
typedef bf16_t bf16x8 __attribute__((ext_vector_type(8)));
typedef float  f32x4  __attribute__((ext_vector_type(4)));

#define N_B     8
#define N_H     128
#define N_W     128
#define N_C     16
#define HID     256
#define N_L     3
#define N_STEPS 16
#define M_TILE  64
#define N_CELLS (N_B * N_H * N_W)
#define K1      160   // conv+fc1 fused K: 144 padded to 160

// XOR swizzle: breaks 512B-row-stride same-bank conflicts on ds_read_b128
// (apply identically on write and read; bijective within each 128B group)
__device__ __forceinline__ int swz(int row, int byteoff) {
  return byteoff ^ ((row & 7) << 4);
}

__global__ void prep_kernel(const float* __restrict__ conv_w,
                            const float* __restrict__ w_first,
                            const float* __restrict__ w_interim,
                            const float* __restrict__ w_last,
                            bf16_t* __restrict__ W1c,
                            bf16_t* __restrict__ Wi,
                            bf16_t* __restrict__ Wl) {
  const int tid = blockIdx.x * blockDim.x + threadIdx.x;
  const int nth = gridDim.x * blockDim.x;
  // W1c[n][k] = sum_o w_first[n][o] * conv_w[o][i][dx+1][dy+1], k=(tap)*16+i
  for (int idx = tid; idx < 256 * K1; idx += nth) {
    int n = idx / K1, k = idx - n * K1;
    float v = 0.f;
    if (k < 144) {
      int tap = k >> 4, i = k & 15;
      int dy = tap / 3 - 1, dx = tap % 3 - 1;
      for (int o = 0; o < 16; ++o)
        v += w_first[n * 16 + o] * conv_w[((o * 16 + i) * 3 + (dx + 1)) * 3 + (dy + 1)];
    }
    W1c[idx] = (bf16_t)v;
  }
  for (int idx = tid; idx < N_L * HID * HID; idx += nth)
    Wi[idx] = (bf16_t)w_interim[idx];
  for (int idx = tid; idx < N_C * HID; idx += nth)
    Wl[idx] = (bf16_t)w_last[idx];
}

// One MLP layer for a 64-row tile: out = relu(in @ Wg^T + bias), N=256.
// Each wave owns a 64-wide N slice; A from LDS (swizzled), B direct from
// global (L2-hot weights), bf16 MFMA 16x16x32, f32 accum.
template <int K>
__device__ __forceinline__ void mlp_layer(const uint8_t* __restrict__ inbuf,
                                          uint8_t* __restrict__ outbuf,
                                          const bf16_t* __restrict__ Wg,
                                          const float* __restrict__ bias,
                                          int lane, int wid) {
  const int lr = lane & 15;   // A-row / B-col / D-col within 16-tile
  const int lk = lane >> 4;   // k-group (8 contiguous bf16)
  const int nbase = wid * 64;
  f32x4 acc[4][4];
#pragma unroll
  for (int nt = 0; nt < 4; ++nt) {
    float bv = bias[nbase + nt * 16 + lr];
    f32x4 binit = {bv, bv, bv, bv};
#pragma unroll
    for (int mt = 0; mt < 4; ++mt) acc[mt][nt] = binit;
  }
#pragma unroll
  for (int kk = 0; kk < K / 32; ++kk) {
    bf16x8 a[4], bfr[4];
    const int kb = kk * 64 + lk * 16;  // byte offset of this lane's 8 bf16
#pragma unroll
    for (int mt = 0; mt < 4; ++mt) {
      int row = mt * 16 + lr;
      a[mt] = *(const bf16x8*)(inbuf + row * 512 + swz(row, kb));
    }
#pragma unroll
    for (int nt = 0; nt < 4; ++nt) {
      int col = nbase + nt * 16 + lr;
      bfr[nt] = *(const bf16x8*)(Wg + col * K + kk * 32 + lk * 8);
    }
#pragma unroll
    for (int mt = 0; mt < 4; ++mt)
#pragma unroll
      for (int nt = 0; nt < 4; ++nt)
        acc[mt][nt] = __builtin_amdgcn_mfma_f32_16x16x32_bf16(a[mt], bfr[nt], acc[mt][nt], 0, 0, 0);
  }
  // relu + cvt + store to out LDS (D layout: col=lane&15, row=4*(lane>>4)+j)
#pragma unroll
  for (int mt = 0; mt < 4; ++mt)
#pragma unroll
    for (int nt = 0; nt < 4; ++nt)
#pragma unroll
      for (int j = 0; j < 4; ++j) {
        int row = mt * 16 + lk * 4 + j;
        int col = nbase + nt * 16 + lr;
        float v = fmaxf(acc[mt][nt][j], 0.f);
        *(bf16_t*)(outbuf + row * 512 + swz(row, col * 2)) = (bf16_t)v;
      }
}

__global__ __launch_bounds__(256, 2)
void nca_step_kernel(const float* __restrict__ hsrc, float* __restrict__ hdst,
                     const bf16_t* __restrict__ W1c, const bf16_t* __restrict__ Wi,
                     const bf16_t* __restrict__ Wl,
                     const float* __restrict__ b_first,
                     const float* __restrict__ b_interim) {
  __shared__ __align__(16) uint8_t buf0[M_TILE * 512];
  __shared__ __align__(16) uint8_t buf1[M_TILE * 512];

  const int t = threadIdx.x;
  const int lane = t & 63;
  const int wid = t >> 6;
  const int cell0 = blockIdx.x * M_TILE;
  const int b = cell0 >> 14;          // /(128*128)
  const int rem = cell0 & 16383;
  const int y = rem >> 7;
  const int x0 = rem & 127;           // 0 or 64; a tile never crosses a row

  // ---- Phase A: build bf16 patch[64][160] into buf1 (rows=cells, k=tap*16+i)
  {
    const int m = t & 63;
    const int q = t >> 6;
    const int x = x0 + m;
#pragma unroll
    for (int j = 0; j < 36; ++j) {
      int k = q * 36 + j;
      int tap = k >> 4, i = k & 15;
      int dy = tap / 3 - 1, dx = tap % 3 - 1;
      int yy = y + dy, xx = x + dx;
      float v = 0.f;
      if ((unsigned)yy < (unsigned)N_H && (unsigned)xx < (unsigned)N_W)
        v = hsrc[((b * N_H + yy) * N_W + xx) * N_C + i];
      *(bf16_t*)(buf1 + m * 512 + swz(m, 2 * k)) = (bf16_t)v;
    }
    // zero k = 144..159 (pad region read by last k-step)
#pragma unroll
    for (int j = 0; j < 4; ++j) {
      int k = 144 + q * 4 + j;
      *(bf16_t*)(buf1 + m * 512 + swz(m, 2 * k)) = (bf16_t)0.f;
    }
  }
  __syncthreads();

  mlp_layer<K1>(buf1, buf0, W1c, b_first, lane, wid);               // conv+fc1
  __syncthreads();
  mlp_layer<HID>(buf0, buf1, Wi + 0 * HID * HID, b_interim + 0 * HID, lane, wid);
  __syncthreads();
  mlp_layer<HID>(buf1, buf0, Wi + 1 * HID * HID, b_interim + 1 * HID, lane, wid);
  __syncthreads();
  mlp_layer<HID>(buf0, buf1, Wi + 2 * HID * HID, b_interim + 2 * HID, lane, wid);
  __syncthreads();

  // ---- Last layer: out[64][16] = act @ w_last^T ; residual in f32
  {
    const int lr = lane & 15;
    const int lk = lane >> 4;
    f32x4 acc = {0.f, 0.f, 0.f, 0.f};
#pragma unroll
    for (int kk = 0; kk < HID / 32; ++kk) {
      int row = wid * 16 + lr;
      bf16x8 a = *(const bf16x8*)(buf1 + row * 512 + swz(row, kk * 64 + lk * 16));
      bf16x8 bb = *(const bf16x8*)(Wl + lr * HID + kk * 32 + lk * 8);
      acc = __builtin_amdgcn_mfma_f32_16x16x32_bf16(a, bb, acc, 0, 0, 0);
    }
#pragma unroll
    for (int j = 0; j < 4; ++j) {
      int row = wid * 16 + lk * 4 + j;
      int gi = (cell0 + row) * N_C + lr;
      hdst[gi] = hsrc[gi] + acc[j];
    }
  }
}

extern "C" void kernel_launch(void* const* d_in, const int* in_sizes, int n_in,
                              void* d_out, int out_size, void* d_ws, size_t ws_size,
                              hipStream_t stream) {
  const float* x         = (const float*)d_in[0];
  const float* conv_w    = (const float*)d_in[1];
  const float* w_first   = (const float*)d_in[2];
  const float* b_first   = (const float*)d_in[3];
  const float* w_interim = (const float*)d_in[4];
  const float* b_interim = (const float*)d_in[5];
  const float* w_last    = (const float*)d_in[6];
  // d_in[7] = steps (scalar, == 16 per reference; fixed at compile time)

  float* xfinal = (float*)d_out;
  float* hist   = xfinal + (size_t)N_CELLS * N_C;  // 17 slots of h-state

  bf16_t* W1c = (bf16_t*)d_ws;          // [256][160]
  bf16_t* Wi  = W1c + 256 * K1;         // [3][256][256]
  bf16_t* Wl  = Wi + N_L * HID * HID;   // [16][256]   (~483 KB total in ws)

  prep_kernel<<<64, 256, 0, stream>>>(conv_w, w_first, w_interim, w_last, W1c, Wi, Wl);
  hipMemcpyAsync(hist, x, (size_t)N_CELLS * N_C * sizeof(float),
                 hipMemcpyDeviceToDevice, stream);
  for (int s = 0; s < N_STEPS; ++s)
    nca_step_kernel<<<N_CELLS / M_TILE, 256, 0, stream>>>(
        hist + (size_t)s * N_CELLS * N_C, hist + (size_t)(s + 1) * N_CELLS * N_C,
        W1c, Wi, Wl, b_first, b_interim);
  hipMemcpyAsync(xfinal, hist + (size_t)N_STEPS * N_CELLS * N_C,
                 (size_t)N_CELLS * N_C * sizeof(float),
                 hipMemcpyDeviceToDevice, stream);
}